// Round 4
// baseline (2912.164 us; speedup 1.0000x reference)
//
#include <hip/hip_runtime.h>
#include <hip/hip_bf16.h>
#include <stdint.h>

#define T_STEPS 63
#define BATCHSZ 32
#define HID 512
#define VOCAB 32000
#define HSZ (BATCHSZ * HID)          /* floats per h snapshot (16384) */

typedef __bf16 bf16x8 __attribute__((ext_vector_type(8)));
typedef float f32x4 __attribute__((ext_vector_type(4)));

__device__ __forceinline__ unsigned short f2bf(float f) {
    __hip_bfloat16 h = __float2bfloat16(f);
    return *reinterpret_cast<unsigned short*>(&h);
}
__device__ __forceinline__ float sigm(float x) { return 1.0f / (1.0f + __expf(-x)); }

// device-coherent accesses (sc0/sc1 at the L3 coherence point; no cache
// maintenance instructions on this path). Mechanism verified in r2/r3.
__device__ __forceinline__ float4 coh16(const float* p) {
    const unsigned long long* q = reinterpret_cast<const unsigned long long*>(p);
    unsigned long long a = __hip_atomic_load(q,     __ATOMIC_RELAXED, __HIP_MEMORY_SCOPE_AGENT);
    unsigned long long b = __hip_atomic_load(q + 1, __ATOMIC_RELAXED, __HIP_MEMORY_SCOPE_AGENT);
    float4 v;
    v.x = __uint_as_float((unsigned)(a & 0xffffffffu));
    v.y = __uint_as_float((unsigned)(a >> 32));
    v.z = __uint_as_float((unsigned)(b & 0xffffffffu));
    v.w = __uint_as_float((unsigned)(b >> 32));
    return v;
}
__device__ __forceinline__ void coh_store(float* p, float v) {
    __hip_atomic_store(p, v, __ATOMIC_RELAXED, __HIP_MEMORY_SCOPE_AGENT);
}

// ---------------------------------------------------------------------------
// grid barrier, zero atomic RMWs (verified r3): block stores monotonic step
// into its own flag; wave0 polls all 256 flags with 4 coalesced relaxed
// loads + ballot. Requires all 256 blocks resident (128KB LDS -> 1 block/CU,
// grid == 256 CUs).
// ---------------------------------------------------------------------------
__device__ __forceinline__ void grid_barrier(unsigned* bar, int bid, unsigned step) {
    __syncthreads();
    const int tid = threadIdx.x;
    if (tid == 0)
        __hip_atomic_store(&bar[bid], step, __ATOMIC_RELAXED, __HIP_MEMORY_SCOPE_AGENT);
    if (tid < 64) {
        const unsigned* f = bar + tid;
        for (;;) {
            unsigned a = __hip_atomic_load(f,       __ATOMIC_RELAXED, __HIP_MEMORY_SCOPE_AGENT);
            unsigned b = __hip_atomic_load(f + 64,  __ATOMIC_RELAXED, __HIP_MEMORY_SCOPE_AGENT);
            unsigned c = __hip_atomic_load(f + 128, __ATOMIC_RELAXED, __HIP_MEMORY_SCOPE_AGENT);
            unsigned d = __hip_atomic_load(f + 192, __ATOMIC_RELAXED, __HIP_MEMORY_SCOPE_AGENT);
            if (__all(a >= step && b >= step && c >= step && d >= step)) break;
            __builtin_amdgcn_s_sleep(1);
        }
        asm volatile("" ::: "memory");
    }
    __syncthreads();
}

// ---------------------------------------------------------------------------
// persistent LSTM. 256 blocks x 512 threads, 1 block/CU.
// bid = layer(2) x jblk(64) x bhalf(2): block owns 8 hidden units x 4 gates,
// K = 1024, for 16 of the 32 batch rows.
// Thread = (u 0..7, seg 0..31, bg 0..1): owns ALL FOUR gate rows of unit
// j0+u over K-cols [seg*32, seg*32+32), for 8 batches (bg half).
//   -> each ds_read_b128 granule feeds 16 FMAs (was 8): compute reads halve.
// Reduction: zero shuffles. Writer stores float4(f,i,c,o) partials to red4
// with bslot = b^u (perfect bank spread); 128 gate threads sum 32 float4s.
// comb granule slot = cg ^ ((cg>>3)&7): stage-write, compute-read, red-write
// and red-read patterns are all analytically conflict-free.
// Staging: issue all 8 coherent loads -> one drain -> 8 ds_writes -> 1 sync.
// Layer-0 x-half prefetched (emb gather for t+1) into the same stg[] regs.
// ---------------------------------------------------------------------------
__global__ __launch_bounds__(512, 1) void lstm_persistent(
    const float* __restrict__ feat, const int* __restrict__ caps,
    const float* __restrict__ emb,
    const float* __restrict__ Wf, const float* __restrict__ bfp,
    const float* __restrict__ Wi, const float* __restrict__ bip,
    const float* __restrict__ Wc, const float* __restrict__ bcp,
    const float* __restrict__ Wo, const float* __restrict__ bop,
    const float* __restrict__ ihw, const float* __restrict__ ihb,
    const float* __restrict__ icw, const float* __restrict__ icb,
    float* h0buf, float* h1buf, unsigned short* h1all, unsigned* bar)
{
    __shared__ alignas(128) float4 comb4[4096];   // 64 KB: 16 rows x 256 slots
    __shared__ alignas(128) float4 red4[4096];    // 64 KB: [bg][seg32][u8][bslot8]

    const int tid = threadIdx.x;
    const int bid = blockIdx.x;
    const int l   = bid >> 7;
    const int sub = bid & 127;
    const int j0  = (sub >> 1) << 3;      // 8 units
    const int b0  = (sub & 1) << 4;       // 16 batches

    const int lane = tid & 63;
    const int u    = lane & 7;            // unit
    const int sl   = lane >> 3;           // seg-low
    const int wv   = tid >> 6;
    const int bg   = wv & 1;              // batch-group (8 batches)
    const int seg  = ((wv >> 1) << 3) | sl;   // 0..31, K-seg of 32 floats
    const int sx   = seg & 7;             // read-side bank rotation

    const int cg    = tid & 255;          // staging granule column (fixed)
    const int bhi   = tid >> 8;
    const int slotW = cg ^ ((cg >> 3) & 7);
    const bool xpf  = (l == 0) && (cg < 128);   // x-half comes from emb prefetch

    // ---- pin weights: 4 gate rows x 32 K-floats = 32 float4 ----
    const size_t rowOff = ((size_t)((l << 9) + j0 + u)) << 10;
    const float4* f4 = reinterpret_cast<const float4*>(Wf + rowOff) + (seg << 3);
    const float4* i4 = reinterpret_cast<const float4*>(Wi + rowOff) + (seg << 3);
    const float4* c4 = reinterpret_cast<const float4*>(Wc + rowOff) + (seg << 3);
    const float4* o4 = reinterpret_cast<const float4*>(Wo + rowOff) + (seg << 3);
    float4 wF[8], wI[8], wC[8], wO[8];
    #pragma unroll
    for (int q = 0; q < 8; ++q) { wF[q]=f4[q]; wI[q]=i4[q]; wC[q]=c4[q]; wO[q]=o4[q]; }

    // ---- init: h0/c0 = feat @ init_{h,c}_w^T + b; c stays in register ----
    float c_reg = 0.f, bf_r = 0.f, bi_r = 0.f, bc_r = 0.f, bo_r = 0.f;
    if (tid < 128) {
        const int uu = tid >> 4, bc = tid & 15;
        const int j = j0 + uu, b = b0 + bc;
        bf_r = bfp[(l << 9) + j];
        bi_r = bip[(l << 9) + j];
        bc_r = bcp[(l << 9) + j];
        bo_r = bop[(l << 9) + j];
        const float4* fr = reinterpret_cast<const float4*>(feat + ((size_t)b << 9));
        const float4* hr = reinterpret_cast<const float4*>(ihw + ((size_t)j << 9));
        const float4* cr = reinterpret_cast<const float4*>(icw + ((size_t)j << 9));
        float sh = 0.f, sc = 0.f;
        #pragma unroll 4
        for (int k = 0; k < 128; ++k) {
            float4 f = fr[k], hv = hr[k], cv = cr[k];
            sh += f.x * hv.x + f.y * hv.y + f.z * hv.z + f.w * hv.w;
            sc += f.x * cv.x + f.y * cv.y + f.z * cv.z + f.w * cv.w;
        }
        sh += ihb[j];
        c_reg = sc + icb[j];
        float* hb = (l == 0 ? h0buf : h1buf) + HSZ;   // parity-1 buffer
        coh_store(&hb[((size_t)b << 9) + j], sh);
    }

    // ---- initial x prefetch (t = 0) for layer-0 x-half threads ----
    float4 stg[8];
    if (xpf) {
        #pragma unroll
        for (int k = 0; k < 8; ++k) {
            int bR = (k << 1) + bhi;
            int tok = caps[(b0 + bR) << 6];
            stg[k] = reinterpret_cast<const float4*>(emb)[(size_t)tok * 128 + cg];
        }
    }
    grid_barrier(bar, bid, 1u);

    // ---- supersteps: layer0 computes t=s (s<63), layer1 computes t=s-1 ----
    for (int s = 0; s < 64; ++s) {
        const bool active = (l == 0) ? (s < 63) : (s >= 1);
        if (active) {
            const int t = (l == 0) ? s : (s - 1);
            const float* h0p = h0buf + (((s + 1) & 1) ? HSZ : 0);
            const float* h1p = h1buf + ((s & 1) ? HSZ : 0);

            // stage: all loads in flight -> one drain -> LDS publish
            if (!xpf) {
                const float* src = (l == 1 && cg >= 128) ? h1p : h0p;
                const int co = (cg & 127) << 2;
                #pragma unroll
                for (int k = 0; k < 8; ++k) {
                    int bR = (k << 1) + bhi;
                    stg[k] = coh16(src + (((size_t)(b0 + bR)) << 9) + co);
                }
            }
            #pragma unroll
            for (int k = 0; k < 8; ++k)
                comb4[(((k << 1) + bhi) << 8) + slotW] = stg[k];
            __syncthreads();

            // compute: 8 batches x 8 granules, 4 gate rows per granule read
            {
                const float4* crb = comb4 + (bg << 11) + (seg << 3);
                #pragma unroll
                for (int b = 0; b < 8; ++b) {
                    uintptr_t base = reinterpret_cast<uintptr_t>(crb + (b << 8))
                                   | (uintptr_t)((unsigned)(sx << 4));
                    float f0=0.f,f1=0.f,i0=0.f,i1=0.f;
                    float c0=0.f,c1=0.f,o0=0.f,o1=0.f;
                    #pragma unroll
                    for (int q = 0; q < 8; ++q) {
                        float4 cc = *reinterpret_cast<const float4*>(
                                        base ^ (uintptr_t)((unsigned)(q << 4)));
                        f0 += wF[q].x*cc.x + wF[q].y*cc.y;  f1 += wF[q].z*cc.z + wF[q].w*cc.w;
                        i0 += wI[q].x*cc.x + wI[q].y*cc.y;  i1 += wI[q].z*cc.z + wI[q].w*cc.w;
                        c0 += wC[q].x*cc.x + wC[q].y*cc.y;  c1 += wC[q].z*cc.z + wC[q].w*cc.w;
                        o0 += wO[q].x*cc.x + wO[q].y*cc.y;  o1 += wO[q].z*cc.z + wO[q].w*cc.w;
                    }
                    red4[(bg << 11) + (seg << 6) + (u << 3) + (b ^ u)] =
                        make_float4(f0 + f1, i0 + i1, c0 + c1, o0 + o1);
                }
            }
            __syncthreads();

            // refill x prefetch for next step (hides emb gather latency)
            if (xpf && s < 62) {
                #pragma unroll
                for (int k = 0; k < 8; ++k) {
                    int bR = (k << 1) + bhi;
                    int tok = caps[((b0 + bR) << 6) + s + 1];
                    stg[k] = reinterpret_cast<const float4*>(emb)[(size_t)tok * 128 + cg];
                }
            }

            // gates: sum 32 seg-partials, nonlinearities, state update
            if (tid < 128) {
                const int uu = tid >> 4, bc = tid & 15;
                const int j = j0 + uu, b = b0 + bc;
                const float4* rr = red4 + ((bc >> 3) << 11) + (uu << 3) + ((bc & 7) ^ uu);
                float sfv = 0.f, siv = 0.f, scv = 0.f, sov = 0.f;
                #pragma unroll
                for (int s2 = 0; s2 < 32; ++s2) {
                    float4 v = rr[s2 << 6];
                    sfv += v.x; siv += v.y; scv += v.z; sov += v.w;
                }
                float fg = sigm(sfv + bf_r), ig = sigm(siv + bi_r);
                float ct = tanhf(scv + bc_r), og = sigm(sov + bo_r);
                float cn = fg * c_reg + ig * ct;
                c_reg = cn;
                float hn = og * tanhf(cn);
                if (l == 0) {
                    coh_store(&h0buf[(s & 1) * HSZ + ((size_t)b << 9) + j], hn);
                } else {
                    coh_store(&h1buf[((s + 1) & 1) * HSZ + ((size_t)b << 9) + j], hn);
                    // M-order = b*63+t so proj_gemm writes sequential rows
                    h1all[((size_t)b * 63 + t) * 512 + j] = f2bf(hn);
                }
            }
        }
        if (s < 63) grid_barrier(bar, bid, (unsigned)(s + 2));
    }
}

// ---------------------------------------------------------------------------
// projection: C(2016 x 32000) = H(2016 x 512) @ out_w^T + out_b, fp32 out.
// H rows already in output order (b*63+t) -> fully sequential row writes.
// 128x128 tile, BK=64, 4 waves of 64x64. (unchanged, verified)
// ---------------------------------------------------------------------------
__global__ __launch_bounds__(256) void proj_gemm(
    const unsigned short* __restrict__ H, const float* __restrict__ W,
    const float* __restrict__ bias, float* __restrict__ out)
{
    __shared__ unsigned short sA[128 * 72];
    __shared__ unsigned short sB[128 * 72];
    const int tid = threadIdx.x;
    const int bm = blockIdx.x, bn = blockIdx.y;
    const int wave = tid >> 6, lane = tid & 63;
    const int wm = (wave >> 1) << 6, wn = (wave & 1) << 6;
    const int lr = lane & 15, quad = lane >> 4;

    f32x4 acc[4][4];
    #pragma unroll
    for (int i = 0; i < 4; ++i)
        #pragma unroll
        for (int j = 0; j < 4; ++j) acc[i][j] = (f32x4){0.f, 0.f, 0.f, 0.f};

    for (int k0 = 0; k0 < 512; k0 += 64) {
        __syncthreads();
        #pragma unroll
        for (int it = 0; it < 4; ++it) {
            int c = tid + (it << 8);
            int row = c >> 3, col = (c & 7) << 3;
            int gm = (bm << 7) + row;
            uint4 av = make_uint4(0u, 0u, 0u, 0u);
            if (gm < 2016)
                av = *reinterpret_cast<const uint4*>(&H[(size_t)gm * 512 + k0 + col]);
            *reinterpret_cast<uint4*>(&sA[row * 72 + col]) = av;
        }
        #pragma unroll
        for (int it = 0; it < 8; ++it) {
            int c = tid + (it << 8);
            int row = c >> 4, col = (c & 15) << 2;
            int gn = (bn << 7) + row;
            float4 bv = *reinterpret_cast<const float4*>(&W[(size_t)gn * 512 + k0 + col]);
            uint2 p;
            p.x = (unsigned int)f2bf(bv.x) | ((unsigned int)f2bf(bv.y) << 16);
            p.y = (unsigned int)f2bf(bv.z) | ((unsigned int)f2bf(bv.w) << 16);
            *reinterpret_cast<uint2*>(&sB[row * 72 + col]) = p;
        }
        __syncthreads();
        #pragma unroll
        for (int ks = 0; ks < 2; ++ks) {
            bf16x8 af[4], bg[4];
            #pragma unroll
            for (int i = 0; i < 4; ++i)
                af[i] = *reinterpret_cast<const bf16x8*>(
                    &sA[(wm + (i << 4) + lr) * 72 + (ks << 5) + (quad << 3)]);
            #pragma unroll
            for (int i = 0; i < 4; ++i)
                bg[i] = *reinterpret_cast<const bf16x8*>(
                    &sB[(wn + (i << 4) + lr) * 72 + (ks << 5) + (quad << 3)]);
            #pragma unroll
            for (int mi = 0; mi < 4; ++mi)
                #pragma unroll
                for (int ni = 0; ni < 4; ++ni)
                    acc[mi][ni] = __builtin_amdgcn_mfma_f32_16x16x32_bf16(
                        af[mi], bg[ni], acc[mi][ni], 0, 0, 0);
        }
    }

    #pragma unroll
    for (int ni = 0; ni < 4; ++ni) {
        int n = (bn << 7) + wn + (ni << 4) + lr;
        float bv = bias[n];
        #pragma unroll
        for (int mi = 0; mi < 4; ++mi) {
            #pragma unroll
            for (int r = 0; r < 4; ++r) {
                int m = (bm << 7) + wm + (mi << 4) + (quad << 2) + r;
                if (m < 2016)
                    out[(size_t)m * VOCAB + n] = acc[mi][ni][r] + bv;
            }
        }
    }
}

extern "C" void kernel_launch(void* const* d_in, const int* in_sizes, int n_in,
                              void* d_out, int out_size, void* d_ws, size_t ws_size,
                              hipStream_t stream) {
    const float* feat = (const float*)d_in[0];
    const int*   caps = (const int*)d_in[1];
    const float* emb  = (const float*)d_in[2];
    const float* Wf   = (const float*)d_in[3];
    const float* bfp  = (const float*)d_in[4];
    const float* Wi   = (const float*)d_in[5];
    const float* bip  = (const float*)d_in[6];
    const float* Wc   = (const float*)d_in[7];
    const float* bcp  = (const float*)d_in[8];
    const float* Wo   = (const float*)d_in[9];
    const float* bop  = (const float*)d_in[10];
    const float* Wout = (const float*)d_in[11];
    const float* bout = (const float*)d_in[12];
    const float* ihw  = (const float*)d_in[13];
    const float* ihb  = (const float*)d_in[14];
    const float* icw  = (const float*)d_in[15];
    const float* icb  = (const float*)d_in[16];

    char* ws = (char*)d_ws;
    unsigned* bar         = (unsigned*)ws;                          // 1 KB flags
    float* h0buf          = (float*)(ws + 1024);                    // 2 x 64 KB
    float* h1buf          = (float*)(ws + 1024 + 131072);           // 2 x 64 KB
    unsigned short* h1all = (unsigned short*)(ws + 1024 + 262144);  // ~2 MB

    hipMemsetAsync(ws, 0, 1024, stream);    // reset flags per replay

    lstm_persistent<<<dim3(256), dim3(512), 0, stream>>>(
        feat, caps, emb, Wf, bfp, Wi, bip, Wc, bcp, Wo, bop,
        ihw, ihb, icw, icb, h0buf, h1buf, h1all, bar);

    proj_gemm<<<dim3(16, 250), dim3(256), 0, stream>>>(h1all, Wout, bout,
                                                       (float*)d_out);
}